// Round 7
// baseline (112.815 us; speedup 1.0000x reference)
//
#include <hip/hip_runtime.h>
#include <cmath>

#define NB 16
#define NA 5
#define NH 152
#define NW 152
#define NT 50
#define NC 20
#define CH 26          // prediction channels
#define TCH 33         // target channels
#define NBT (NB * NT)  // 800 (b,t) pairs
#define NCELL (NB * NA * NH * NW)   // 1,848,320 conf cells
#define NG 3610        // granules of 3328 float4 (= 512 cells each); NG*3328 == TOT4
#define NBLK 1792      // stream blocks (7 per CU), grid-stride over granules

// anchors / SCALE
__device__ __constant__ float c_aw[NA] = {4.f, 8.f, 16.f, 24.f, 12.f};
__device__ __constant__ float c_ah[NA] = {4.f, 8.f, 16.f, 12.f, 24.f};

// packed word: bits0-7 gi | 8-15 gj | 16-20 ignore mask | 21-25 best_n one-hot | 26 valid
#define VALID_BIT (1u << 26)

__device__ __forceinline__ float bce0(float l) {  // bce(logit, target=0)
  const float e = exp2f(fabsf(l) * -1.4426950408889634f);
  return fmaxf(l, 0.f) + 0.69314718055994531f * log2f(1.f + e);
}

// ws float layout: [0..16) acc (0-3 coord, 4 ce, 5 n_obj, 6 s_ob, 7 s_sub_mask, 8 n_mask)
//                  [64..864)     packed words (800)
//                  [1024..2816)  partials (NBLK, fully overwritten)

__global__ __launch_bounds__(256) void k_main(
    const float* __restrict__ pred, const float* __restrict__ tgt,
    const int* __restrict__ tsz, float* __restrict__ acc,
    unsigned* __restrict__ packed_out, float* __restrict__ partials) {
  const int tid = threadIdx.x;

  if (blockIdx.x < NBLK) {
    // ------- m13-shaped stream: grid-stride granules, 13 deep loads -------
    const float4* p4 = (const float4*)pred;
    const int r = tid % 13;   // iteration-invariant residue
    float s = 0.f;
    for (int g = blockIdx.x; g < NG; g += NBLK) {
      const size_t base = (size_t)g * 3328 + tid;
      const float4 v0  = p4[base];
      const float4 v1  = p4[base + 256];
      const float4 v2  = p4[base + 512];
      const float4 v3  = p4[base + 768];
      const float4 v4  = p4[base + 1024];
      const float4 v5  = p4[base + 1280];
      const float4 v6  = p4[base + 1536];
      const float4 v7  = p4[base + 1792];
      const float4 v8  = p4[base + 2048];
      const float4 v9  = p4[base + 2304];
      const float4 v10 = p4[base + 2560];
      const float4 v11 = p4[base + 2816];
      const float4 v12 = p4[base + 3072];
      // residue of load k: (r + 9k) mod 13. Exactly one k gives 0 (take .x,
      // float 4q = even cell conf) and one gives 6 (take .z, odd cell conf).
      float c0 = 0.f, c6 = 0.f;
      c0 = (r == 0)  ? v0.x  : c0;   c6 = (r == 6)  ? v0.z  : c6;
      c0 = (r == 4)  ? v1.x  : c0;   c6 = (r == 10) ? v1.z  : c6;
      c0 = (r == 8)  ? v2.x  : c0;   c6 = (r == 1)  ? v2.z  : c6;
      c0 = (r == 12) ? v3.x  : c0;   c6 = (r == 5)  ? v3.z  : c6;
      c0 = (r == 3)  ? v4.x  : c0;   c6 = (r == 9)  ? v4.z  : c6;
      c0 = (r == 7)  ? v5.x  : c0;   c6 = (r == 0)  ? v5.z  : c6;
      c0 = (r == 11) ? v6.x  : c0;   c6 = (r == 4)  ? v6.z  : c6;
      c0 = (r == 2)  ? v7.x  : c0;   c6 = (r == 8)  ? v7.z  : c6;
      c0 = (r == 6)  ? v8.x  : c0;   c6 = (r == 12) ? v8.z  : c6;
      c0 = (r == 10) ? v9.x  : c0;   c6 = (r == 3)  ? v9.z  : c6;
      c0 = (r == 1)  ? v10.x : c0;   c6 = (r == 7)  ? v10.z : c6;
      c0 = (r == 5)  ? v11.x : c0;   c6 = (r == 11) ? v11.z : c6;
      c0 = (r == 9)  ? v12.x : c0;   c6 = (r == 2)  ? v12.z : c6;
      s += bce0(c0) + bce0(c6);
    }
    for (int off = 32; off >= 1; off >>= 1) s += __shfl_down(s, off, 64);
    __shared__ float sw[4];
    if ((tid & 63) == 0) sw[tid >> 6] = s;
    __syncthreads();
    if (tid == 0) partials[blockIdx.x] = sw[0] + sw[1] + sw[2] + sw[3];
    return;
  }

  // ---------------- targets block (blockIdx == NBLK) ----------------------
  __shared__ unsigned s_packed[NBT];
  __shared__ float s_acc[9];
  if (tid < 9) s_acc[tid] = 0.f;

  #pragma unroll
  for (int k = 0; k < 4; ++k) {
    const int bt = tid + k * 256;
    if (bt < NBT) {
      const int b = bt / NT, t = bt - b * NT;
      const float* tr = tgt + (size_t)bt * TCH;
      const float gx = tr[0] * 0.25f, gy = tr[1] * 0.25f;
      const float gh = tr[3] * 0.25f, gw = tr[4] * 0.25f;
      const bool valid = (t < tsz[b]) && (gw > 0.f) && (gh > 0.f);
      const int gi = min(max((int)gx, 0), NW - 1);
      const int gj = min(max((int)gy, 0), NH - 1);
      const float area_gt = (gw + 1.f) * (gh + 1.f);
      float best = -1.f; int bestn = 0; unsigned amask = 0;
      for (int a = 0; a < NA; ++a) {
        const float inter = (fminf(gw, c_aw[a]) + 1.f) * (fminf(gh, c_ah[a]) + 1.f);
        const float area_a = (c_aw[a] + 1.f) * (c_ah[a] + 1.f);
        const float iou = inter / (area_gt + area_a - inter + 1e-16f);
        if (iou > best) { best = iou; bestn = a; }   // first-max tie-break
        if (iou > 0.5f) amask |= (1u << a);
      }
      unsigned word = 0;
      if (valid)
        word = (unsigned)gi | ((unsigned)gj << 8) | (amask << 16) |
               (1u << (21 + bestn)) | VALID_BIT;
      s_packed[bt] = word;
      packed_out[bt] = word;
    }
  }
  __syncthreads();

  float cx = 0, cy = 0, cw = 0, chh = 0, cce = 0, cn = 0;
  float s_ob = 0, s_sub = 0, n_msk = 0;
  #pragma unroll
  for (int k = 0; k < 4; ++k) {
    const int bt = tid + k * 256;
    if (bt < NBT) {
      const unsigned word = s_packed[bt];
      if (word & VALID_BIT) {
        const int b = bt / NT, t = bt - b * NT;
        const unsigned keymask = 0xFFFFu | (0x1Fu << 21);
        const unsigned mykey = word & keymask;
        bool winner = true;  // last-update-wins per (cell, best_n)
        for (int t2 = t + 1; t2 < NT; ++t2) {
          const unsigned w2 = s_packed[b * NT + t2];
          if ((w2 & VALID_BIT) && ((w2 & keymask) == mykey)) { winner = false; break; }
        }
        if (winner) {
          const int gi = word & 0xFF, gj = (word >> 8) & 0xFF;
          const int bestn = __ffs((word >> 21) & 0x1F) - 1;
          const float* tr = tgt + (size_t)bt * TCH;
          const float gx = tr[0] * 0.25f, gy = tr[1] * 0.25f;
          const float gh = tr[3] * 0.25f, gw = tr[4] * 0.25f;
          const float txv = atanhf(gx - ((float)gi + 0.5f));
          const float tyv = atanhf(gy - ((float)gj + 0.5f));
          const float twv = logf(gw / c_aw[bestn] + 1e-16f);
          const float thv = logf(gh / c_ah[bestn] + 1e-16f);
          float bc = tr[13]; int label = 0;
          for (int c = 1; c < NC; ++c)
            if (tr[13 + c] > bc) { bc = tr[13 + c]; label = c; }
          const float* p = pred + ((((size_t)b * NA + bestn) * NH + gj) * NW + gi) * CH;
          const float l0 = p[0];
          cx  += (p[1] - txv) * (p[1] - txv);
          cy  += (p[2] - tyv) * (p[2] - tyv);
          chh += (p[4] - thv) * (p[4] - thv);
          cw  += (p[5] - twv) * (p[5] - twv);
          float m = p[6];
          for (int c = 1; c < NC; ++c) m = fmaxf(m, p[6 + c]);
          float se = 0.f;
          for (int c = 0; c < NC; ++c) se += expf(p[6 + c] - m);
          cce += (m + logf(se)) - p[6 + label];
          cn += 1.f;
          const float b0 = bce0(l0);
          s_ob  += b0 - l0;   // bce(l,1) = bce(l,0) - l
          s_sub += b0;        // remove mask cell from noobj sum
          n_msk += 1.f;
        }
      }
    }
  }

  for (int off = 32; off >= 1; off >>= 1) {
    cx  += __shfl_down(cx, off, 64);   cy    += __shfl_down(cy, off, 64);
    cw  += __shfl_down(cw, off, 64);   chh   += __shfl_down(chh, off, 64);
    cce += __shfl_down(cce, off, 64);  cn    += __shfl_down(cn, off, 64);
    s_ob+= __shfl_down(s_ob, off, 64); s_sub += __shfl_down(s_sub, off, 64);
    n_msk += __shfl_down(n_msk, off, 64);
  }
  if ((tid & 63) == 0) {
    atomicAdd(&s_acc[0], cx);   atomicAdd(&s_acc[1], cy);
    atomicAdd(&s_acc[2], cw);   atomicAdd(&s_acc[3], chh);
    atomicAdd(&s_acc[4], cce);  atomicAdd(&s_acc[5], cn);
    atomicAdd(&s_acc[6], s_ob); atomicAdd(&s_acc[7], s_sub);
    atomicAdd(&s_acc[8], n_msk);
  }
  __syncthreads();
  if (tid < 9) acc[tid] = s_acc[tid];
}

__global__ __launch_bounds__(1024) void k_fin(
    const float* __restrict__ pred, const unsigned* __restrict__ packed,
    const float* __restrict__ acc, const float* __restrict__ partials,
    float* __restrict__ out) {
  __shared__ unsigned s_packed[NBT];
  __shared__ float sw[3][16];
  const int tid = threadIdx.x;
  if (tid < NBT) s_packed[tid] = packed[tid];
  float s_all = 0.f;
  for (int i = tid; i < NBLK; i += 1024) s_all += partials[i];
  __syncthreads();

  // ignored-not-masked cells: first-wins dedupe per (cell, anchor), idempotent
  float s_ign = 0.f, n_ign = 0.f;
  for (int u = tid; u < NBT * NA; u += 1024) {
    const int bt = u / NA, a = u - bt * NA;
    const unsigned w = s_packed[bt];
    if (!(w & VALID_BIT) || !((w >> (16 + a)) & 1u)) continue;
    const int b = bt / NT, t = bt - b * NT;
    const unsigned key = w & 0xFFFFu;
    bool skip = false;
    for (int t2 = 0; t2 < t; ++t2) {   // earlier target already claims it
      const unsigned w2 = s_packed[b * NT + t2];
      if ((w2 & VALID_BIT) && ((w2 & 0xFFFFu) == key) && ((w2 >> (16 + a)) & 1u)) { skip = true; break; }
    }
    if (skip) continue;
    for (int t2 = 0; t2 < NT; ++t2) {  // masked by any target -> handled via mask path
      const unsigned w2 = s_packed[b * NT + t2];
      if ((w2 & VALID_BIT) && ((w2 & 0xFFFFu) == key) && ((w2 >> (21 + a)) & 1u)) { skip = true; break; }
    }
    if (skip) continue;
    const int gi = w & 0xFF, gj = (w >> 8) & 0xFF;
    s_ign += bce0(pred[((((size_t)b * NA + a) * NH + gj) * NW + gi) * CH]);
    n_ign += 1.f;
  }

  for (int off = 32; off >= 1; off >>= 1) {
    s_all += __shfl_down(s_all, off, 64);
    s_ign += __shfl_down(s_ign, off, 64);
    n_ign += __shfl_down(n_ign, off, 64);
  }
  const int wv = tid >> 6;
  if ((tid & 63) == 0) { sw[0][wv] = s_all; sw[1][wv] = s_ign; sw[2][wv] = n_ign; }
  __syncthreads();
  if (tid == 0) {
    float a0 = 0, a1 = 0, a2 = 0;
    for (int i = 0; i < 16; ++i) { a0 += sw[0][i]; a1 += sw[1][i]; a2 += sw[2][i]; }
    const float n_obj = fmaxf(acc[5], 1.f);
    const float n_noobj = fmaxf((float)NCELL - acc[8] - a2, 1.f);
    out[0] = (acc[0] + acc[1] + acc[2] + acc[3] + acc[4] + acc[6]) / n_obj +
             1.25f * (a0 - acc[7] - a1) / n_noobj;
  }
}

extern "C" void kernel_launch(void* const* d_in, const int* in_sizes, int n_in,
                              void* d_out, int out_size, void* d_ws, size_t ws_size,
                              hipStream_t stream) {
  const float* pred = (const float*)d_in[0];
  const float* tgt = (const float*)d_in[1];
  const int* tsz = (const int*)d_in[2];
  float* out = (float*)d_out;
  float* acc = (float*)d_ws;
  unsigned* packed = (unsigned*)((float*)d_ws + 64);
  float* partials = (float*)d_ws + 1024;

  k_main<<<NBLK + 1, 256, 0, stream>>>(pred, tgt, tsz, acc, packed, partials);
  k_fin<<<1, 1024, 0, stream>>>(pred, packed, acc, partials, out);
}

// Round 8
// 112.216 us; speedup vs baseline: 1.0053x; 1.0053x over previous
//
#include <hip/hip_runtime.h>
#include <cmath>

#define NB 16
#define NA 5
#define NH 152
#define NW 152
#define NT 50
#define NC 20
#define CH 26          // prediction channels
#define TCH 33         // target channels
#define NBT (NB * NT)  // 800 (b,t) pairs
#define NCELL (NB * NA * NH * NW)   // 1,848,320 conf cells
#define CPB 1024                    // cells per stream block
#define NSB (NCELL / CPB)           // 1805 stream blocks (exact)
#define NPART (NSB * 4)             // per-wave partials

// anchors / SCALE
__device__ __constant__ float c_aw[NA] = {4.f, 8.f, 16.f, 24.f, 12.f};
__device__ __constant__ float c_ah[NA] = {4.f, 8.f, 16.f, 12.f, 24.f};

// packed word: bits0-7 gi | 8-15 gj | 16-20 ignore mask | 21-25 best_n one-hot | 26 valid
#define VALID_BIT (1u << 26)

__device__ __forceinline__ float bce0(float l) {  // bce(logit, target=0)
  const float e = exp2f(fabsf(l) * -1.4426950408889634f);
  return fmaxf(l, 0.f) + 0.69314718055994531f * log2f(1.f + e);
}

// ws float layout: [0..16) acc (0-3 coord, 4 ce, 5 n_obj, 6 s_ob, 7 s_sub_mask, 8 n_mask)
//                  [64..864)     packed words (800)
//                  [1024..8244)  per-wave partials (NPART, fully overwritten)

__global__ __launch_bounds__(256) void k_main(
    const float* __restrict__ pred, const float* __restrict__ tgt,
    const int* __restrict__ tsz, float* __restrict__ acc,
    unsigned* __restrict__ packed_out, float* __restrict__ partials) {
  __shared__ float s_conf[CPB];        // gathered conf logits (4 KB)
  __shared__ unsigned s_packed[NBT];
  __shared__ float s_acc[9];
  const int tid = threadIdx.x;

  if (blockIdx.x < NSB) {
    // ---- async scatter-gather: per-lane global addr -> linear LDS ----
    const int w = tid >> 6, lane = tid & 63;
    const size_t cell0 = (size_t)blockIdx.x * CPB;
    #pragma unroll
    for (int k = 0; k < 4; ++k) {
      const size_t g = cell0 + (size_t)(w * 256 + k * 64 + lane);
      const float* gp = pred + g * CH;               // conf of cell g
      __builtin_amdgcn_global_load_lds(
          (__attribute__((address_space(1))) unsigned int*)gp,
          (__attribute__((address_space(3))) unsigned int*)&s_conf[w * 256 + k * 64],
          4, 0, 0);
    }
    asm volatile("s_waitcnt vmcnt(0)" ::: "memory");
    __builtin_amdgcn_sched_barrier(0);
    // each thread reads 4 floats written by ITS OWN wave -> no barrier needed
    const float4 v = *(const float4*)&s_conf[tid * 4];
    float s = bce0(v.x) + bce0(v.y) + bce0(v.z) + bce0(v.w);
    for (int off = 32; off >= 1; off >>= 1) s += __shfl_down(s, off, 64);
    if (lane == 0) partials[blockIdx.x * 4 + w] = s;
    return;
  }

  // ---------------- targets block (blockIdx == NSB) ----------------------
  if (tid < 9) s_acc[tid] = 0.f;

  #pragma unroll
  for (int k = 0; k < 4; ++k) {
    const int bt = tid + k * 256;
    if (bt < NBT) {
      const int b = bt / NT, t = bt - b * NT;
      const float* tr = tgt + (size_t)bt * TCH;
      const float gx = tr[0] * 0.25f, gy = tr[1] * 0.25f;
      const float gh = tr[3] * 0.25f, gw = tr[4] * 0.25f;
      const bool valid = (t < tsz[b]) && (gw > 0.f) && (gh > 0.f);
      const int gi = min(max((int)gx, 0), NW - 1);
      const int gj = min(max((int)gy, 0), NH - 1);
      const float area_gt = (gw + 1.f) * (gh + 1.f);
      float best = -1.f; int bestn = 0; unsigned amask = 0;
      for (int a = 0; a < NA; ++a) {
        const float inter = (fminf(gw, c_aw[a]) + 1.f) * (fminf(gh, c_ah[a]) + 1.f);
        const float area_a = (c_aw[a] + 1.f) * (c_ah[a] + 1.f);
        const float iou = inter / (area_gt + area_a - inter + 1e-16f);
        if (iou > best) { best = iou; bestn = a; }   // first-max tie-break
        if (iou > 0.5f) amask |= (1u << a);
      }
      unsigned word = 0;
      if (valid)
        word = (unsigned)gi | ((unsigned)gj << 8) | (amask << 16) |
               (1u << (21 + bestn)) | VALID_BIT;
      s_packed[bt] = word;
      packed_out[bt] = word;
    }
  }
  __syncthreads();

  float cx = 0, cy = 0, cw = 0, chh = 0, cce = 0, cn = 0;
  float s_ob = 0, s_sub = 0, n_msk = 0;
  #pragma unroll
  for (int k = 0; k < 4; ++k) {
    const int bt = tid + k * 256;
    if (bt < NBT) {
      const unsigned word = s_packed[bt];
      if (word & VALID_BIT) {
        const int b = bt / NT, t = bt - b * NT;
        const unsigned keymask = 0xFFFFu | (0x1Fu << 21);
        const unsigned mykey = word & keymask;
        bool winner = true;  // last-update-wins per (cell, best_n)
        for (int t2 = t + 1; t2 < NT; ++t2) {
          const unsigned w2 = s_packed[b * NT + t2];
          if ((w2 & VALID_BIT) && ((w2 & keymask) == mykey)) { winner = false; break; }
        }
        if (winner) {
          const int gi = word & 0xFF, gj = (word >> 8) & 0xFF;
          const int bestn = __ffs((word >> 21) & 0x1F) - 1;
          const float* tr = tgt + (size_t)bt * TCH;
          const float gx = tr[0] * 0.25f, gy = tr[1] * 0.25f;
          const float gh = tr[3] * 0.25f, gw = tr[4] * 0.25f;
          const float txv = atanhf(gx - ((float)gi + 0.5f));
          const float tyv = atanhf(gy - ((float)gj + 0.5f));
          const float twv = logf(gw / c_aw[bestn] + 1e-16f);
          const float thv = logf(gh / c_ah[bestn] + 1e-16f);
          float bc = tr[13]; int label = 0;
          for (int c = 1; c < NC; ++c)
            if (tr[13 + c] > bc) { bc = tr[13 + c]; label = c; }
          const float* p = pred + ((((size_t)b * NA + bestn) * NH + gj) * NW + gi) * CH;
          const float l0 = p[0];
          cx  += (p[1] - txv) * (p[1] - txv);
          cy  += (p[2] - tyv) * (p[2] - tyv);
          chh += (p[4] - thv) * (p[4] - thv);
          cw  += (p[5] - twv) * (p[5] - twv);
          float m = p[6];
          for (int c = 1; c < NC; ++c) m = fmaxf(m, p[6 + c]);
          float se = 0.f;
          for (int c = 0; c < NC; ++c) se += expf(p[6 + c] - m);
          cce += (m + logf(se)) - p[6 + label];
          cn += 1.f;
          const float b0 = bce0(l0);
          s_ob  += b0 - l0;   // bce(l,1) = bce(l,0) - l
          s_sub += b0;        // remove mask cell from noobj sum
          n_msk += 1.f;
        }
      }
    }
  }

  for (int off = 32; off >= 1; off >>= 1) {
    cx  += __shfl_down(cx, off, 64);   cy    += __shfl_down(cy, off, 64);
    cw  += __shfl_down(cw, off, 64);   chh   += __shfl_down(chh, off, 64);
    cce += __shfl_down(cce, off, 64);  cn    += __shfl_down(cn, off, 64);
    s_ob+= __shfl_down(s_ob, off, 64); s_sub += __shfl_down(s_sub, off, 64);
    n_msk += __shfl_down(n_msk, off, 64);
  }
  if ((tid & 63) == 0) {
    atomicAdd(&s_acc[0], cx);   atomicAdd(&s_acc[1], cy);
    atomicAdd(&s_acc[2], cw);   atomicAdd(&s_acc[3], chh);
    atomicAdd(&s_acc[4], cce);  atomicAdd(&s_acc[5], cn);
    atomicAdd(&s_acc[6], s_ob); atomicAdd(&s_acc[7], s_sub);
    atomicAdd(&s_acc[8], n_msk);
  }
  __syncthreads();
  if (tid < 9) acc[tid] = s_acc[tid];
}

__global__ __launch_bounds__(1024) void k_fin(
    const float* __restrict__ pred, const unsigned* __restrict__ packed,
    const float* __restrict__ acc, const float* __restrict__ partials,
    float* __restrict__ out) {
  __shared__ unsigned s_packed[NBT];
  __shared__ float sw[3][16];
  const int tid = threadIdx.x;
  if (tid < NBT) s_packed[tid] = packed[tid];
  float s_all = 0.f;
  for (int i = tid; i < NPART; i += 1024) s_all += partials[i];
  __syncthreads();

  // ignored-not-masked cells: first-wins dedupe per (cell, anchor), idempotent
  float s_ign = 0.f, n_ign = 0.f;
  for (int u = tid; u < NBT * NA; u += 1024) {
    const int bt = u / NA, a = u - bt * NA;
    const unsigned w = s_packed[bt];
    if (!(w & VALID_BIT) || !((w >> (16 + a)) & 1u)) continue;
    const int b = bt / NT, t = bt - b * NT;
    const unsigned key = w & 0xFFFFu;
    bool skip = false;
    for (int t2 = 0; t2 < t; ++t2) {   // earlier target already claims it
      const unsigned w2 = s_packed[b * NT + t2];
      if ((w2 & VALID_BIT) && ((w2 & 0xFFFFu) == key) && ((w2 >> (16 + a)) & 1u)) { skip = true; break; }
    }
    if (skip) continue;
    for (int t2 = 0; t2 < NT; ++t2) {  // masked by any target -> handled via mask path
      const unsigned w2 = s_packed[b * NT + t2];
      if ((w2 & VALID_BIT) && ((w2 & 0xFFFFu) == key) && ((w2 >> (21 + a)) & 1u)) { skip = true; break; }
    }
    if (skip) continue;
    const int gi = w & 0xFF, gj = (w >> 8) & 0xFF;
    s_ign += bce0(pred[((((size_t)b * NA + a) * NH + gj) * NW + gi) * CH]);
    n_ign += 1.f;
  }

  for (int off = 32; off >= 1; off >>= 1) {
    s_all += __shfl_down(s_all, off, 64);
    s_ign += __shfl_down(s_ign, off, 64);
    n_ign += __shfl_down(n_ign, off, 64);
  }
  const int wv = tid >> 6;
  if ((tid & 63) == 0) { sw[0][wv] = s_all; sw[1][wv] = s_ign; sw[2][wv] = n_ign; }
  __syncthreads();
  if (tid == 0) {
    float a0 = 0, a1 = 0, a2 = 0;
    for (int i = 0; i < 16; ++i) { a0 += sw[0][i]; a1 += sw[1][i]; a2 += sw[2][i]; }
    const float n_obj = fmaxf(acc[5], 1.f);
    const float n_noobj = fmaxf((float)NCELL - acc[8] - a2, 1.f);
    out[0] = (acc[0] + acc[1] + acc[2] + acc[3] + acc[4] + acc[6]) / n_obj +
             1.25f * (a0 - acc[7] - a1) / n_noobj;
  }
}

extern "C" void kernel_launch(void* const* d_in, const int* in_sizes, int n_in,
                              void* d_out, int out_size, void* d_ws, size_t ws_size,
                              hipStream_t stream) {
  const float* pred = (const float*)d_in[0];
  const float* tgt = (const float*)d_in[1];
  const int* tsz = (const int*)d_in[2];
  float* out = (float*)d_out;
  float* acc = (float*)d_ws;
  unsigned* packed = (unsigned*)((float*)d_ws + 64);
  float* partials = (float*)d_ws + 1024;

  k_main<<<NSB + 1, 256, 0, stream>>>(pred, tgt, tsz, acc, packed, partials);
  k_fin<<<1, 1024, 0, stream>>>(pred, packed, acc, partials, out);
}

// Round 9
// 92.506 us; speedup vs baseline: 1.2195x; 1.2131x over previous
//
#include <hip/hip_runtime.h>
#include <cmath>

#define NB 16
#define NA 5
#define NH 152
#define NW 152
#define NT 50
#define NC 20
#define CH 26            // prediction channels
#define TCH 33           // target channels
#define NBT (NB * NT)    // 800 (b,t) pairs
#define NCELL (NB * NA * NH * NW)   // 1,848,320 conf cells
#define NROW (NB * NA * NH)         // 12,160 rows of NW cells
#define ROWF4 988                   // float4 per row (152*26/4)

// anchors / SCALE
__device__ __constant__ float c_aw[NA] = {4.f, 8.f, 16.f, 24.f, 12.f};
__device__ __constant__ float c_ah[NA] = {4.f, 8.f, 16.f, 12.f, 24.f};

// packed word: bits0-7 gi | 8-15 gj | 16-20 ignore mask | 21-25 best_n one-hot | 26 valid
#define VALID_BIT (1u << 26)

__device__ __forceinline__ float bce0(float l) {  // bce(logit, target=0)
  const float e = exp2f(fabsf(l) * -1.4426950408889634f);
  return fmaxf(l, 0.f) + 0.69314718055994531f * log2f(1.f + e);
}

// ws float layout: [0..12160) partials, fully overwritten every call

// ---------------------------------------------------------------------------
// Lean stream (R2's proven shape, s_match removed): one block per (b,a,j) row,
// 988 float4, guarded 4-iteration loop, conf extracted via even-residue check.
// ---------------------------------------------------------------------------
__global__ __launch_bounds__(256) void k_conf(
    const float* __restrict__ pred, float* __restrict__ partials) {
  const float4* row = (const float4*)(pred + (size_t)blockIdx.x * (ROWF4 * 4));
  float s = 0.f;
  int q = threadIdx.x;
  int m = (4 * q) % 26;          // residue of float index 4q (always even)
  #pragma unroll
  for (int k = 0; k < 4; ++k) {
    if (q < ROWF4) {
      const float4 v = row[q];
      if (m == 0) s += bce0(v.x);        // float 4q   -> channel 0
      else if (m == 24) s += bce0(v.z);  // float 4q+2 -> channel 0
    }
    q += 256;
    m += 10; if (m >= 26) m -= 26;       // 1024 mod 26 == 10
  }
  for (int off = 32; off >= 1; off >>= 1) s += __shfl_down(s, off, 64);
  __shared__ float sw[4];
  if ((threadIdx.x & 63) == 0) sw[threadIdx.x >> 6] = s;
  __syncthreads();
  if (threadIdx.x == 0) partials[blockIdx.x] = sw[0] + sw[1] + sw[2] + sw[3];
}

// ---------------------------------------------------------------------------
// Single-block finisher: targets -> winners (coord/CE/mask) -> ignore dedupe
// -> partials sum -> combine. Logic verbatim from the absmax-0.0 kernels.
// ---------------------------------------------------------------------------
__global__ __launch_bounds__(1024) void k_rest(
    const float* __restrict__ pred, const float* __restrict__ tgt,
    const int* __restrict__ tsz, const float* __restrict__ partials,
    float* __restrict__ out) {
  __shared__ unsigned s_packed[NBT];
  __shared__ float sred[12][16];
  const int tid = threadIdx.x;

  // --- phase 1: pack targets ---
  if (tid < NBT) {
    const int b = tid / NT, t = tid - b * NT;
    const float* tr = tgt + (size_t)tid * TCH;
    const float gx = tr[0] * 0.25f, gy = tr[1] * 0.25f;
    const float gh = tr[3] * 0.25f, gw = tr[4] * 0.25f;
    const bool valid = (t < tsz[b]) && (gw > 0.f) && (gh > 0.f);
    const int gi = min(max((int)gx, 0), NW - 1);
    const int gj = min(max((int)gy, 0), NH - 1);
    const float area_gt = (gw + 1.f) * (gh + 1.f);
    float best = -1.f; int bestn = 0; unsigned amask = 0;
    for (int a = 0; a < NA; ++a) {
      const float inter = (fminf(gw, c_aw[a]) + 1.f) * (fminf(gh, c_ah[a]) + 1.f);
      const float area_a = (c_aw[a] + 1.f) * (c_ah[a] + 1.f);
      const float iou = inter / (area_gt + area_a - inter + 1e-16f);
      if (iou > best) { best = iou; bestn = a; }   // first-max tie-break
      if (iou > 0.5f) amask |= (1u << a);
    }
    unsigned word = 0;
    if (valid)
      word = (unsigned)gi | ((unsigned)gj << 8) | (amask << 16) |
             (1u << (21 + bestn)) | VALID_BIT;
    s_packed[tid] = word;
  }
  __syncthreads();

  // --- phase 2: winners (last-update-wins per (cell, best_n)) ---
  float cx = 0, cy = 0, cw = 0, chh = 0, cce = 0, cn = 0;
  float s_ob = 0, s_sub = 0, n_msk = 0;
  if (tid < NBT) {
    const unsigned word = s_packed[tid];
    if (word & VALID_BIT) {
      const int b = tid / NT, t = tid - b * NT;
      const unsigned keymask = 0xFFFFu | (0x1Fu << 21);
      const unsigned mykey = word & keymask;
      bool winner = true;
      for (int t2 = t + 1; t2 < NT; ++t2) {
        const unsigned w2 = s_packed[b * NT + t2];
        if ((w2 & VALID_BIT) && ((w2 & keymask) == mykey)) { winner = false; break; }
      }
      if (winner) {
        const int gi = word & 0xFF, gj = (word >> 8) & 0xFF;
        const int bestn = __ffs((word >> 21) & 0x1F) - 1;
        const float* tr = tgt + (size_t)tid * TCH;
        const float gx = tr[0] * 0.25f, gy = tr[1] * 0.25f;
        const float gh = tr[3] * 0.25f, gw = tr[4] * 0.25f;
        const float txv = atanhf(gx - ((float)gi + 0.5f));
        const float tyv = atanhf(gy - ((float)gj + 0.5f));
        const float twv = logf(gw / c_aw[bestn] + 1e-16f);
        const float thv = logf(gh / c_ah[bestn] + 1e-16f);
        float bc = tr[13]; int label = 0;
        for (int c = 1; c < NC; ++c)
          if (tr[13 + c] > bc) { bc = tr[13 + c]; label = c; }
        const float* p = pred + ((((size_t)b * NA + bestn) * NH + gj) * NW + gi) * CH;
        const float l0 = p[0];
        cx  += (p[1] - txv) * (p[1] - txv);
        cy  += (p[2] - tyv) * (p[2] - tyv);
        chh += (p[4] - thv) * (p[4] - thv);
        cw  += (p[5] - twv) * (p[5] - twv);
        float mm = p[6];
        for (int c = 1; c < NC; ++c) mm = fmaxf(mm, p[6 + c]);
        float se = 0.f;
        for (int c = 0; c < NC; ++c) se += expf(p[6 + c] - mm);
        cce += (mm + logf(se)) - p[6 + label];
        cn += 1.f;
        const float b0 = bce0(l0);
        s_ob  += b0 - l0;   // bce(l,1) = bce(l,0) - l
        s_sub += b0;        // remove mask cell from noobj sum
        n_msk += 1.f;
      }
    }
  }

  // --- phase 3: ignored-not-masked cells (first-wins dedupe per cell,anchor) ---
  float s_ign = 0.f, n_ign = 0.f;
  for (int u = tid; u < NBT * NA; u += 1024) {
    const int bt = u / NA, a = u - bt * NA;
    const unsigned w = s_packed[bt];
    if (!(w & VALID_BIT) || !((w >> (16 + a)) & 1u)) continue;
    const int b = bt / NT, t = bt - b * NT;
    const unsigned key = w & 0xFFFFu;
    bool skip = false;
    for (int t2 = 0; t2 < t; ++t2) {
      const unsigned w2 = s_packed[b * NT + t2];
      if ((w2 & VALID_BIT) && ((w2 & 0xFFFFu) == key) && ((w2 >> (16 + a)) & 1u)) { skip = true; break; }
    }
    if (skip) continue;
    for (int t2 = 0; t2 < NT; ++t2) {
      const unsigned w2 = s_packed[b * NT + t2];
      if ((w2 & VALID_BIT) && ((w2 & 0xFFFFu) == key) && ((w2 >> (21 + a)) & 1u)) { skip = true; break; }
    }
    if (skip) continue;
    const int gi = w & 0xFF, gj = (w >> 8) & 0xFF;
    s_ign += bce0(pred[((((size_t)b * NA + a) * NH + gj) * NW + gi) * CH]);
    n_ign += 1.f;
  }

  // --- phase 4: sum stream partials ---
  float s_all = 0.f;
  for (int i = tid; i < NROW; i += 1024) s_all += partials[i];

  // --- phase 5: reduce 12 accumulators and combine ---
  for (int off = 32; off >= 1; off >>= 1) {
    cx    += __shfl_down(cx, off, 64);    cy    += __shfl_down(cy, off, 64);
    cw    += __shfl_down(cw, off, 64);    chh   += __shfl_down(chh, off, 64);
    cce   += __shfl_down(cce, off, 64);   cn    += __shfl_down(cn, off, 64);
    s_ob  += __shfl_down(s_ob, off, 64);  s_sub += __shfl_down(s_sub, off, 64);
    n_msk += __shfl_down(n_msk, off, 64); s_ign += __shfl_down(s_ign, off, 64);
    n_ign += __shfl_down(n_ign, off, 64); s_all += __shfl_down(s_all, off, 64);
  }
  const int wv = tid >> 6;
  if ((tid & 63) == 0) {
    sred[0][wv] = cx;    sred[1][wv] = cy;    sred[2][wv] = cw;
    sred[3][wv] = chh;   sred[4][wv] = cce;   sred[5][wv] = cn;
    sred[6][wv] = s_ob;  sred[7][wv] = s_sub; sred[8][wv] = n_msk;
    sred[9][wv] = s_ign; sred[10][wv] = n_ign; sred[11][wv] = s_all;
  }
  __syncthreads();
  if (tid == 0) {
    float a[12];
    for (int j = 0; j < 12; ++j) {
      float x = 0.f;
      for (int i = 0; i < 16; ++i) x += sred[j][i];
      a[j] = x;
    }
    const float n_obj = fmaxf(a[5], 1.f);
    const float n_noobj = fmaxf((float)NCELL - a[8] - a[10], 1.f);
    out[0] = (a[0] + a[1] + a[2] + a[3] + a[4] + a[6]) / n_obj +
             1.25f * (a[11] - a[7] - a[9]) / n_noobj;
  }
}

extern "C" void kernel_launch(void* const* d_in, const int* in_sizes, int n_in,
                              void* d_out, int out_size, void* d_ws, size_t ws_size,
                              hipStream_t stream) {
  const float* pred = (const float*)d_in[0];
  const float* tgt = (const float*)d_in[1];
  const int* tsz = (const int*)d_in[2];
  float* out = (float*)d_out;
  float* partials = (float*)d_ws;   // NROW floats, fully overwritten

  k_conf<<<NROW, 256, 0, stream>>>(pred, partials);
  k_rest<<<1, 1024, 0, stream>>>(pred, tgt, tsz, partials, out);
}